// Round 3
// baseline (48.114 us; speedup 1.0000x reference)
//
#include <hip/hip_runtime.h>

#define HW 196
#define C  384
#define TK 98
#define NT 1024
#define NWAVE (NT/64)      // 16
#define NQUAD ((HW+3)/4)   // 49, and 49*4 == 196 exactly (no tail)

__global__ __launch_bounds__(NT) void sampling_kernel(
    const float* __restrict__ token,
    const float* __restrict__ feature,
    float* __restrict__ out)
{
    __shared__ float tokLds[C];
    __shared__ float score[HW];
    __shared__ float selW[TK];
    __shared__ int   selIdx[TK];
    __shared__ float wsum[NWAVE];
    __shared__ float part[NWAVE][C];   // 24 KB: per-wave pass-2 partials
    __shared__ float s_max, s_winv;

    const int tid  = threadIdx.x;
    const int wave = tid >> 6;
    const int lane = tid & 63;
    const int pair = blockIdx.x;

    const float* tokp  = token   + (size_t)pair * C;
    const float* featp = feature + (size_t)pair * (HW * C);

    // stage token row (384 f32) in LDS
    for (int i = tid; i < C; i += NT) tokLds[i] = tokp[i];
    __syncthreads();

    // per-lane token fragment in registers (reused for all 196 rows)
    const float4* t4 = (const float4*)tokLds;
    float4 tb  = t4[lane];
    float4 tb2 = make_float4(0.f, 0.f, 0.f, 0.f);
    if (lane < 32) tb2 = t4[64 + lane];

    const float scale = 0.05103103630798288f;  // 384^-0.5

    // ---- pass 1: scores, 4 rows per wave-iteration for MLP ----
    // Each lane issues 6 independent float4 loads (96 B) before reducing.
    for (int q = wave; q < NQUAD; q += NWAVE) {
        const int rbase = q * 4;
        float4 a[4], b[4];
        #pragma unroll
        for (int j = 0; j < 4; ++j) {
            const float4* f4 = (const float4*)(featp + (rbase + j) * C);
            a[j] = f4[lane];
            if (lane < 32) b[j] = f4[64 + lane];
        }
        #pragma unroll
        for (int j = 0; j < 4; ++j) {
            float p = a[j].x*tb.x + a[j].y*tb.y + a[j].z*tb.z + a[j].w*tb.w;
            if (lane < 32)
                p += b[j].x*tb2.x + b[j].y*tb2.y + b[j].z*tb2.z + b[j].w*tb2.w;
            #pragma unroll
            for (int off = 32; off > 0; off >>= 1)
                p += __shfl_xor(p, off, 64);
            if (lane == 0) score[rbase + j] = p * scale;
        }
    }
    __syncthreads();

    // ---- max over 196 scores (wave 0) ----
    if (wave == 0) {
        float m = -3.4e38f;
        for (int i = lane; i < HW; i += 64) m = fmaxf(m, score[i]);
        #pragma unroll
        for (int off = 32; off > 0; off >>= 1)
            m = fmaxf(m, __shfl_xor(m, off, 64));
        if (lane == 0) s_max = m;
    }
    __syncthreads();

    // ---- rank-by-counting (jax.lax.top_k stable tie-break) + compact ----
    // Softmax denom cancels under renormalization: weight = exp(s - max).
    float w = 0.f;
    if (tid < HW) {
        const float si = score[tid];
        int rank = 0;
        for (int j = 0; j < HW; ++j) {
            const float sj = score[j];                 // LDS broadcast
            rank += (int)((sj > si) | ((sj == si) & (j < tid)));
        }
        if (rank < TK) {
            w = __expf(si - s_max);
            selIdx[rank] = tid;
            selW[rank]  = w;
        }
    }
    #pragma unroll
    for (int off = 32; off > 0; off >>= 1) w += __shfl_xor(w, off, 64);
    if (lane == 0) wsum[wave] = w;
    __syncthreads();
    if (tid == 0) {
        float s = 0.f;
        #pragma unroll
        for (int i = 0; i < NWAVE; ++i) s += wsum[i];
        s_winv = 1.f / s;
    }
    __syncthreads();

    // ---- pass 2: each wave owns selected rows i = wave, wave+16, ... ----
    float4 acc_a = make_float4(0.f, 0.f, 0.f, 0.f);
    float4 acc_b = make_float4(0.f, 0.f, 0.f, 0.f);
    for (int i = wave; i < TK; i += NWAVE) {
        const int   r   = selIdx[i];
        const float wgt = selW[i];
        const float4* f4 = (const float4*)(featp + (size_t)r * C);
        float4 a = f4[lane];
        acc_a.x += wgt * a.x; acc_a.y += wgt * a.y;
        acc_a.z += wgt * a.z; acc_a.w += wgt * a.w;
        if (lane < 32) {
            float4 b = f4[64 + lane];
            acc_b.x += wgt * b.x; acc_b.y += wgt * b.y;
            acc_b.z += wgt * b.z; acc_b.w += wgt * b.w;
        }
    }
    float4* pw = (float4*)&part[wave][0];
    pw[lane] = acc_a;
    if (lane < 32) pw[64 + lane] = acc_b;
    __syncthreads();

    // ---- 16-way cross-wave reduction, coalesced store ----
    if (tid < C) {
        float s = 0.f;
        #pragma unroll
        for (int wv = 0; wv < NWAVE; ++wv) s += part[wv][tid];
        out[(size_t)pair * C + tid] = s * s_winv;
    }
}

extern "C" void kernel_launch(void* const* d_in, const int* in_sizes, int n_in,
                              void* d_out, int out_size, void* d_ws, size_t ws_size,
                              hipStream_t stream) {
    const float* token   = (const float*)d_in[0];
    const float* feature = (const float*)d_in[1];
    float* out = (float*)d_out;
    const int pairs = in_sizes[0] / C;   // 8*16*4 = 512
    sampling_kernel<<<pairs, NT, 0, stream>>>(token, feature, out);
}

// Round 4
// 39.142 us; speedup vs baseline: 1.2292x; 1.2292x over previous
//
#include <hip/hip_runtime.h>

#define HW 196
#define C  384
#define CF4 (C/4)          // 96 float4 per row
#define TK 98
#define NT 512
#define NWAVE (NT/64)      // 8

__global__ __launch_bounds__(NT, 4) void sampling_kernel(
    const float* __restrict__ token,
    const float* __restrict__ feature,
    float* __restrict__ out)
{
    __shared__ float tokLds[C];
    __shared__ float score[HW];
    __shared__ float selW[TK];
    __shared__ int   selIdx[TK];
    __shared__ float wsum[NWAVE];
    __shared__ float part[NWAVE][C];   // 12 KB per-wave pass-2 partials
    __shared__ float s_max, s_winv;

    const int tid  = threadIdx.x;
    const int wave = tid >> 6;
    const int lane = tid & 63;
    const int g    = lane >> 2;        // 4-lane group 0..15
    const int l    = lane & 3;         // sub-lane within group
    const int pair = blockIdx.x;

    const float* tokp  = token   + (size_t)pair * C;
    const float* featp = feature + (size_t)pair * (HW * C);
    const float4* f4base = (const float4*)featp;
    const float4* t4     = (const float4*)tokLds;

    // stage token row (384 f32) in LDS
    for (int i = tid; i < C; i += NT) tokLds[i] = tokp[i];
    __syncthreads();

    const float scale = 0.05103103630798288f;  // 384^-0.5

    // ---- pass 1: 4 lanes per row; each lane runs 24 independent float4
    // loads (stride 64B) with only 2 shuffles at the end of the row. ----
    #pragma unroll
    for (int strip = 0; strip < 2; ++strip) {
        const int r = strip * 128 + wave * 16 + g;
        if (r < HW) {
            const float4* f4 = f4base + (size_t)r * CF4;
            float4 acc = make_float4(0.f, 0.f, 0.f, 0.f);
            #pragma unroll
            for (int k = 0; k < 24; ++k) {
                float4 a = f4[l + 4 * k];     // 64B-contiguous per group
                float4 t = t4[l + 4 * k];     // LDS broadcast across groups
                acc.x += a.x * t.x; acc.y += a.y * t.y;
                acc.z += a.z * t.z; acc.w += a.w * t.w;
            }
            float s = (acc.x + acc.y) + (acc.z + acc.w);
            s += __shfl_xor(s, 1, 64);
            s += __shfl_xor(s, 2, 64);
            if (l == 0) score[r] = s * scale;
        }
    }
    __syncthreads();

    // ---- max over 196 scores (wave 0) ----
    if (wave == 0) {
        float m = -3.4e38f;
        for (int i = lane; i < HW; i += 64) m = fmaxf(m, score[i]);
        #pragma unroll
        for (int off = 32; off > 0; off >>= 1)
            m = fmaxf(m, __shfl_xor(m, off, 64));
        if (lane == 0) s_max = m;
    }
    __syncthreads();

    // ---- rank-by-counting (jax.lax.top_k stable tie-break) + compact ----
    // Softmax denom cancels under renormalization: weight = exp(s - max).
    float w = 0.f;
    if (tid < HW) {
        const float si = score[tid];
        int rank = 0;
        for (int j = 0; j < HW; ++j) {
            const float sj = score[j];                 // LDS broadcast
            rank += (int)((sj > si) | ((sj == si) & (j < tid)));
        }
        if (rank < TK) {
            w = __expf(si - s_max);
            selIdx[rank] = tid;
            selW[rank]  = w;
        }
    }
    #pragma unroll
    for (int off = 32; off > 0; off >>= 1) w += __shfl_xor(w, off, 64);
    if (lane == 0) wsum[wave] = w;
    __syncthreads();
    if (tid == 0) {
        float s = 0.f;
        #pragma unroll
        for (int i = 0; i < NWAVE; ++i) s += wsum[i];
        s_winv = 1.f / s;
    }
    __syncthreads();

    // ---- pass 2: weighted sum, 4 rows unrolled per wave-iteration ----
    float4 acc_a = make_float4(0.f, 0.f, 0.f, 0.f);
    float4 acc_b = make_float4(0.f, 0.f, 0.f, 0.f);
    for (int base = wave; base < TK; base += 4 * NWAVE) {
        #pragma unroll
        for (int j = 0; j < 4; ++j) {
            const int i = base + j * NWAVE;
            if (i < TK) {
                const int   r   = selIdx[i];
                const float wgt = selW[i];
                const float4* f4 = f4base + (size_t)r * CF4;
                float4 a = f4[lane];
                acc_a.x += wgt * a.x; acc_a.y += wgt * a.y;
                acc_a.z += wgt * a.z; acc_a.w += wgt * a.w;
                if (lane < 32) {
                    float4 b = f4[64 + lane];
                    acc_b.x += wgt * b.x; acc_b.y += wgt * b.y;
                    acc_b.z += wgt * b.z; acc_b.w += wgt * b.w;
                }
            }
        }
    }
    float4* pw = (float4*)&part[wave][0];
    pw[lane] = acc_a;
    if (lane < 32) pw[64 + lane] = acc_b;
    __syncthreads();

    // ---- 8-way cross-wave reduction, coalesced store ----
    if (tid < C) {
        float s = 0.f;
        #pragma unroll
        for (int wv = 0; wv < NWAVE; ++wv) s += part[wv][tid];
        out[(size_t)pair * C + tid] = s * s_winv;
    }
}

extern "C" void kernel_launch(void* const* d_in, const int* in_sizes, int n_in,
                              void* d_out, int out_size, void* d_ws, size_t ws_size,
                              hipStream_t stream) {
    const float* token   = (const float*)d_in[0];
    const float* feature = (const float*)d_in[1];
    float* out = (float*)d_out;
    const int pairs = in_sizes[0] / C;   // 8*16*4 = 512
    sampling_kernel<<<pairs, NT, 0, stream>>>(token, feature, out);
}

// Round 5
// 38.496 us; speedup vs baseline: 1.2499x; 1.0168x over previous
//
#include <hip/hip_runtime.h>

#define HW 196
#define C  384
#define CF4 (C/4)          // 96 float4 per row
#define TK 98
#define NT 512
#define NWAVE (NT/64)      // 8

__global__ __launch_bounds__(NT, 4) void sampling_kernel(
    const float* __restrict__ token,
    const float* __restrict__ feature,
    float* __restrict__ out)
{
    __shared__ float tokLds[C];
    __shared__ float score[HW];
    __shared__ float selW[TK];
    __shared__ int   selIdx[TK];
    __shared__ float wsum[NWAVE];
    __shared__ int   rank2[2 * HW];
    __shared__ float part[NWAVE][C];   // 12 KB per-wave pass-2 partials
    __shared__ float s_max, s_winv;

    const int tid  = threadIdx.x;
    const int wave = tid >> 6;
    const int lane = tid & 63;
    const int g    = lane >> 2;        // 4-lane group 0..15
    const int l    = lane & 3;         // sub-lane within group
    const int pair = blockIdx.x;

    const float* tokp  = token   + (size_t)pair * C;
    const float* featp = feature + (size_t)pair * (HW * C);
    const float4* f4base = (const float4*)featp;
    const float4* t4     = (const float4*)tokLds;

    // stage token row (384 f32) in LDS
    for (int i = tid; i < C; i += NT) tokLds[i] = tokp[i];
    __syncthreads();

    const float scale = 0.05103103630798288f;  // 384^-0.5

    // ---- pass 1: 4 lanes per row. Burst ALL 24 float4 loads for the row
    // (imm offsets off one per-lane base) BEFORE any FMA; sched_barrier
    // prevents the scheduler from sinking loads into the compute. ----
    {
        const int r0 = wave * 16 + g;                       // 0..127
        const float4* f0 = f4base + (size_t)r0 * CF4 + l;   // per-lane base
        float4 a[12], b[12];
        #pragma unroll
        for (int k = 0; k < 12; ++k) a[k] = f0[4 * k];
        #pragma unroll
        for (int k = 0; k < 12; ++k) b[k] = f0[4 * (k + 12)];
        __builtin_amdgcn_sched_barrier(0);
        float4 acc = make_float4(0.f, 0.f, 0.f, 0.f);
        #pragma unroll
        for (int k = 0; k < 12; ++k) {
            float4 t = t4[l + 4 * k];
            acc.x += a[k].x * t.x; acc.y += a[k].y * t.y;
            acc.z += a[k].z * t.z; acc.w += a[k].w * t.w;
        }
        #pragma unroll
        for (int k = 0; k < 12; ++k) {
            float4 t = t4[l + 4 * (k + 12)];
            acc.x += b[k].x * t.x; acc.y += b[k].y * t.y;
            acc.z += b[k].z * t.z; acc.w += b[k].w * t.w;
        }
        float s = (acc.x + acc.y) + (acc.z + acc.w);
        s += __shfl_xor(s, 1, 64);
        s += __shfl_xor(s, 2, 64);
        if (l == 0) score[r0] = s * scale;

        // strip 2: rows 128..195 (groups 0..67 only)
        if (r0 < HW - 128) {
            const int r1 = 128 + r0;
            const float4* f1 = f4base + (size_t)r1 * CF4 + l;
            #pragma unroll
            for (int k = 0; k < 12; ++k) a[k] = f1[4 * k];
            #pragma unroll
            for (int k = 0; k < 12; ++k) b[k] = f1[4 * (k + 12)];
            __builtin_amdgcn_sched_barrier(0);
            float4 acc1 = make_float4(0.f, 0.f, 0.f, 0.f);
            #pragma unroll
            for (int k = 0; k < 12; ++k) {
                float4 t = t4[l + 4 * k];
                acc1.x += a[k].x * t.x; acc1.y += a[k].y * t.y;
                acc1.z += a[k].z * t.z; acc1.w += a[k].w * t.w;
            }
            #pragma unroll
            for (int k = 0; k < 12; ++k) {
                float4 t = t4[l + 4 * (k + 12)];
                acc1.x += b[k].x * t.x; acc1.y += b[k].y * t.y;
                acc1.z += b[k].z * t.z; acc1.w += b[k].w * t.w;
            }
            float s1 = (acc1.x + acc1.y) + (acc1.z + acc1.w);
            s1 += __shfl_xor(s1, 1, 64);
            s1 += __shfl_xor(s1, 2, 64);
            if (l == 0) score[r1] = s1 * scale;
        }
    }
    __syncthreads();

    // ---- concurrent: threads 0..391 rank-count (half-range each);
    //      wave 7 computes the max. ----
    if (tid < 2 * HW) {
        const int i = tid >> 1, h = tid & 1;
        const float si = score[i];
        int cnt = 0;
        const int j0 = h * (HW / 2);
        for (int j = j0; j < j0 + HW / 2; ++j) {
            const float sj = score[j];
            cnt += (int)((sj > si) | ((sj == si) & (j < i)));
        }
        rank2[tid] = cnt;
    } else if (wave == NWAVE - 1) {
        float m = -3.4e38f;
        for (int i = lane; i < HW; i += 64) m = fmaxf(m, score[i]);
        #pragma unroll
        for (int off = 32; off > 0; off >>= 1)
            m = fmaxf(m, __shfl_xor(m, off, 64));
        if (lane == 0) s_max = m;
    }
    __syncthreads();

    // ---- select + compact (softmax denom cancels: w = exp(s - max)) ----
    float w = 0.f;
    if (tid < HW) {
        const int rank = rank2[2 * tid] + rank2[2 * tid + 1];
        if (rank < TK) {
            w = __expf(score[tid] - s_max);
            selIdx[rank] = tid;
            selW[rank]  = w;
        }
    }
    #pragma unroll
    for (int off = 32; off > 0; off >>= 1) w += __shfl_xor(w, off, 64);
    if (lane == 0) wsum[wave] = w;
    __syncthreads();
    if (tid == 0) {
        float s = 0.f;
        #pragma unroll
        for (int i = 0; i < NWAVE; ++i) s += wsum[i];
        s_winv = 1.f / s;
    }
    __syncthreads();

    // ---- pass 2: weighted sum over 98 selected rows (L2-resident).
    // Static 12-iter unroll + 2-row tail; full-wave coalesced rows. ----
    float4 acc_a = make_float4(0.f, 0.f, 0.f, 0.f);
    float4 acc_b = make_float4(0.f, 0.f, 0.f, 0.f);
    #pragma unroll
    for (int j = 0; j < 12; ++j) {
        const int i = wave + NWAVE * j;          // 0..95
        const int   r   = selIdx[i];
        const float wgt = selW[i];
        const float4* f4 = f4base + (size_t)r * CF4;
        float4 aa = f4[lane];
        acc_a.x += wgt * aa.x; acc_a.y += wgt * aa.y;
        acc_a.z += wgt * aa.z; acc_a.w += wgt * aa.w;
        if (lane < 32) {
            float4 bb = f4[64 + lane];
            acc_b.x += wgt * bb.x; acc_b.y += wgt * bb.y;
            acc_b.z += wgt * bb.z; acc_b.w += wgt * bb.w;
        }
    }
    if (wave < TK - 96) {                         // rows 96, 97
        const int i = 96 + wave;
        const int   r   = selIdx[i];
        const float wgt = selW[i];
        const float4* f4 = f4base + (size_t)r * CF4;
        float4 aa = f4[lane];
        acc_a.x += wgt * aa.x; acc_a.y += wgt * aa.y;
        acc_a.z += wgt * aa.z; acc_a.w += wgt * aa.w;
        if (lane < 32) {
            float4 bb = f4[64 + lane];
            acc_b.x += wgt * bb.x; acc_b.y += wgt * bb.y;
            acc_b.z += wgt * bb.z; acc_b.w += wgt * bb.w;
        }
    }
    float4* pw = (float4*)&part[wave][0];
    pw[lane] = acc_a;
    if (lane < 32) pw[64 + lane] = acc_b;
    __syncthreads();

    // ---- 8-way cross-wave reduction, coalesced store ----
    if (tid < C) {
        float s = 0.f;
        #pragma unroll
        for (int wv = 0; wv < NWAVE; ++wv) s += part[wv][tid];
        out[(size_t)pair * C + tid] = s * s_winv;
    }
}

extern "C" void kernel_launch(void* const* d_in, const int* in_sizes, int n_in,
                              void* d_out, int out_size, void* d_ws, size_t ws_size,
                              hipStream_t stream) {
    const float* token   = (const float*)d_in[0];
    const float* feature = (const float*)d_in[1];
    float* out = (float*)d_out;
    const int pairs = in_sizes[0] / C;   // 8*16*4 = 512
    sampling_kernel<<<pairs, NT, 0, stream>>>(token, feature, out);
}

// Round 6
// 38.112 us; speedup vs baseline: 1.2625x; 1.0101x over previous
//
#include <hip/hip_runtime.h>

#define HW 196
#define C  384
#define CF4 (C/4)          // 96 float4 per row
#define TK 98
#define NT 512
#define NWAVE (NT/64)      // 8

__global__ __launch_bounds__(NT, 4) void sampling_kernel(
    const float* __restrict__ token,
    const float* __restrict__ feature,
    float* __restrict__ out)
{
    __shared__ float tokLds[C];
    __shared__ float score[HW];
    __shared__ float selW[TK];
    __shared__ int   selIdx[TK];
    __shared__ float wsum[NWAVE];
    __shared__ int   rank2[2 * HW];
    __shared__ float part[NWAVE][C];   // 12 KB per-wave pass-2 partials
    __shared__ float s_max, s_winv;

    const int tid  = threadIdx.x;
    const int wave = tid >> 6;
    const int lane = tid & 63;
    const int l8   = lane & 7;         // sub-lane within 8-lane group
    const int g8   = lane >> 3;        // group 0..7 within wave
    const int pair = blockIdx.x;

    const float* tokp  = token   + (size_t)pair * C;
    const float* featp = feature + (size_t)pair * (HW * C);
    const float4* f4base = (const float4*)featp;
    const float4* t4     = (const float4*)tokLds;

    // stage token row (384 f32) in LDS
    for (int i = tid; i < C; i += NT) tokLds[i] = tokp[i];
    __syncthreads();

    // this lane's token column-slice in registers: cols l8 + 8k (k=0..11)
    float4 tok[12];
    #pragma unroll
    for (int k = 0; k < 12; ++k) tok[k] = t4[l8 + 8 * k];

    const float scale = 0.05103103630798288f;  // 384^-0.5

    // ---- pass 1: 8-lane group per row; 64 groups -> 3 balanced iters.
    // Each lane: 12 independent float4 loads (128B-contiguous per group),
    // FMA against register-held token, 3 shuffles per row. ----
    #pragma unroll
    for (int it = 0; it < 3; ++it) {
        const int r = it * 64 + wave * 8 + g8;          // 0..191, balanced
        const float4* fr = f4base + (size_t)r * CF4 + l8;
        float4 a[12];
        #pragma unroll
        for (int k = 0; k < 12; ++k) a[k] = fr[8 * k];
        float4 acc = make_float4(0.f, 0.f, 0.f, 0.f);
        #pragma unroll
        for (int k = 0; k < 12; ++k) {
            acc.x += a[k].x * tok[k].x; acc.y += a[k].y * tok[k].y;
            acc.z += a[k].z * tok[k].z; acc.w += a[k].w * tok[k].w;
        }
        float s = (acc.x + acc.y) + (acc.z + acc.w);
        s += __shfl_xor(s, 1, 64);
        s += __shfl_xor(s, 2, 64);
        s += __shfl_xor(s, 4, 64);
        if (l8 == 0) score[r] = s * scale;
    }
    // tail rows 192..195: group 0 of waves 0..3
    if (wave < 4 && g8 == 0) {
        const int r = 192 + wave;
        const float4* fr = f4base + (size_t)r * CF4 + l8;
        float4 acc = make_float4(0.f, 0.f, 0.f, 0.f);
        #pragma unroll
        for (int k = 0; k < 12; ++k) {
            float4 a = fr[8 * k];
            acc.x += a.x * tok[k].x; acc.y += a.y * tok[k].y;
            acc.z += a.z * tok[k].z; acc.w += a.w * tok[k].w;
        }
        float s = (acc.x + acc.y) + (acc.z + acc.w);
        s += __shfl_xor(s, 1, 64);
        s += __shfl_xor(s, 2, 64);
        s += __shfl_xor(s, 4, 64);
        if (l8 == 0) score[r] = s * scale;
    }
    __syncthreads();

    // ---- concurrent: threads 0..391 rank-count (half-range each);
    //      wave 7 computes the max. ----
    if (tid < 2 * HW) {
        const int i = tid >> 1, h = tid & 1;
        const float si = score[i];
        int cnt = 0;
        const int j0 = h * (HW / 2);
        for (int j = j0; j < j0 + HW / 2; ++j) {
            const float sj = score[j];
            cnt += (int)((sj > si) | ((sj == si) & (j < i)));
        }
        rank2[tid] = cnt;
    } else if (wave == NWAVE - 1) {
        float m = -3.4e38f;
        for (int i = lane; i < HW; i += 64) m = fmaxf(m, score[i]);
        #pragma unroll
        for (int off = 32; off > 0; off >>= 1)
            m = fmaxf(m, __shfl_xor(m, off, 64));
        if (lane == 0) s_max = m;
    }
    __syncthreads();

    // ---- select + compact (softmax denom cancels: w = exp(s - max)) ----
    float w = 0.f;
    if (tid < HW) {
        const int rank = rank2[2 * tid] + rank2[2 * tid + 1];
        if (rank < TK) {
            w = __expf(score[tid] - s_max);
            selIdx[rank] = tid;
            selW[rank]  = w;
        }
    }
    #pragma unroll
    for (int off = 32; off > 0; off >>= 1) w += __shfl_xor(w, off, 64);
    if (lane == 0) wsum[wave] = w;
    __syncthreads();
    if (tid == 0) {
        float s = 0.f;
        #pragma unroll
        for (int i = 0; i < NWAVE; ++i) s += wsum[i];
        s_winv = 1.f / s;
    }
    __syncthreads();

    // ---- pass 2: weighted sum over 98 selected rows (L2/L3-resident).
    // Static 12-iter unroll + 2-row tail; full-wave coalesced rows. ----
    float4 acc_a = make_float4(0.f, 0.f, 0.f, 0.f);
    float4 acc_b = make_float4(0.f, 0.f, 0.f, 0.f);
    #pragma unroll
    for (int j = 0; j < 12; ++j) {
        const int i = wave + NWAVE * j;          // 0..95
        const int   r   = selIdx[i];
        const float wgt = selW[i];
        const float4* f4 = f4base + (size_t)r * CF4;
        float4 aa = f4[lane];
        acc_a.x += wgt * aa.x; acc_a.y += wgt * aa.y;
        acc_a.z += wgt * aa.z; acc_a.w += wgt * aa.w;
        if (lane < 32) {
            float4 bb = f4[64 + lane];
            acc_b.x += wgt * bb.x; acc_b.y += wgt * bb.y;
            acc_b.z += wgt * bb.z; acc_b.w += wgt * bb.w;
        }
    }
    if (wave < TK - 96) {                         // rows 96, 97
        const int i = 96 + wave;
        const int   r   = selIdx[i];
        const float wgt = selW[i];
        const float4* f4 = f4base + (size_t)r * CF4;
        float4 aa = f4[lane];
        acc_a.x += wgt * aa.x; acc_a.y += wgt * aa.y;
        acc_a.z += wgt * aa.z; acc_a.w += wgt * aa.w;
        if (lane < 32) {
            float4 bb = f4[64 + lane];
            acc_b.x += wgt * bb.x; acc_b.y += wgt * bb.y;
            acc_b.z += wgt * bb.z; acc_b.w += wgt * bb.w;
        }
    }
    float4* pw = (float4*)&part[wave][0];
    pw[lane] = acc_a;
    if (lane < 32) pw[64 + lane] = acc_b;
    __syncthreads();

    // ---- 8-way cross-wave reduction, coalesced store ----
    if (tid < C) {
        float s = 0.f;
        #pragma unroll
        for (int wv = 0; wv < NWAVE; ++wv) s += part[wv][tid];
        out[(size_t)pair * C + tid] = s * s_winv;
    }
}

extern "C" void kernel_launch(void* const* d_in, const int* in_sizes, int n_in,
                              void* d_out, int out_size, void* d_ws, size_t ws_size,
                              hipStream_t stream) {
    const float* token   = (const float*)d_in[0];
    const float* feature = (const float*)d_in[1];
    float* out = (float*)d_out;
    const int pairs = in_sizes[0] / C;   // 8*16*4 = 512
    sampling_kernel<<<pairs, NT, 0, stream>>>(token, feature, out);
}